// Round 9
// baseline (315.541 us; speedup 1.0000x reference)
//
#include <hip/hip_runtime.h>

typedef _Float16 half2v __attribute__((ext_vector_type(2)));
typedef _Float16 half8  __attribute__((ext_vector_type(8)));
typedef float    floatx4 __attribute__((ext_vector_type(4)));

#define M_DIM 64
#define K_DIM 8192
#define N_DIM 8192
#define NT 512              // cols per block (8 waves x 64 cols)
#define KSB 16              // k-chunks; chunk = 512 k = 4 stages x 128 k
#define REPS 4              // PROBE (this round): in-kernel repeat to surface
                            // mm in rocprof top-5 with its own counters.

// x fp32 [64][8192] -> xp fp16 tiled [k/32][mt:4][lane:64][j:8]
// j-order within each 8 is sigma=(0,4,1,5,2,6,3,7) matching B nibble unpack.
__global__ __launch_bounds__(256) void permute_x_kernel(
        const float* __restrict__ x, _Float16* __restrict__ xp) {
    const int t  = blockIdx.x * 256 + threadIdx.x;
    const int c  = t & 15;
    const int q  = (t >> 4) & 3;
    const int mt = (t >> 6) & 3;
    const int kb = t >> 8;
    const int m  = mt * 16 + c;
    const int k0 = kb * 32 + q * 8;
    const float* src = x + (size_t)m * K_DIM + k0;
    float4 a = *(const float4*)(src);
    float4 b = *(const float4*)(src + 4);
    union { _Float16 h[8]; float4 f; } u;
    u.h[0] = (_Float16)a.x; u.h[1] = (_Float16)b.x;
    u.h[2] = (_Float16)a.y; u.h[3] = (_Float16)b.y;
    u.h[4] = (_Float16)a.z; u.h[5] = (_Float16)b.z;
    u.h[6] = (_Float16)a.w; u.h[7] = (_Float16)b.w;
    *(float4*)(xp + (size_t)t * 8) = u.f;
}

__device__ __forceinline__ void dma16(const void* g, void* l) {
    __builtin_amdgcn_global_load_lds(
        (const __attribute__((address_space(1))) unsigned int*)(uintptr_t)g,
        (__attribute__((address_space(3))) unsigned int*)(uintptr_t)l,
        16, 0, 0);
}

__device__ __forceinline__ half2v dq_pair(unsigned int bits, half2v sub, half2v sc) {
    union { unsigned int u; half2v h; } cv;
    cv.u = bits;
    return (cv.h - sub) * sc;      // v_pk_add_f16 + v_pk_mul_f16
}

__global__ __launch_bounds__(512, 4) void machete_mm_kernel(
        const _Float16* __restrict__ xp,
        const unsigned int* __restrict__ Bq,
        const float* __restrict__ s,
        _Float16* __restrict__ partial) {
    __shared__ char astage[2][16384];                // A stage dbuf, 32 KB

    const int tid  = threadIdx.x;
    const int w    = tid >> 6;                       // wave 0..7, n-split
    const int lane = tid & 63;
    const int c    = lane & 15;
    const int q    = lane >> 4;
    const int ns   = blockIdx.x;                     // n-strip 0..15
    const int kb   = blockIdx.y;                     // k-chunk 0..15
    const int wc   = ns * NT + w * 64;               // wave's 64-col base

    const half2v c1032 = { (_Float16)1032.0f, (_Float16)1032.0f };

    const char* a_base = (const char*)xp + (size_t)kb * 65536;
    const unsigned int* b_base = Bq + (size_t)(kb * 64) * N_DIM + wc + c;
    const float*        s_base = s + (size_t)(kb * 4) * N_DIM + wc + c;

    auto bload = [&](int st, int d, int t) {
        return b_base[(size_t)(st * 16 + d * 4 + q) * N_DIM + 16 * t];
    };
    auto stage_dma = [&](int st, int p) {            // wave w copies 2x1KB
        #pragma unroll
        for (int k = 0; k < 2; ++k) {
            const int idx = k * 8 + w;
            dma16(a_base + (size_t)st * 16384 + idx * 1024 + lane * 16,
                  &astage[p][idx * 1024]);
        }
    };

    for (int rep = 0; rep < REPS; ++rep) {           // PROBE loop — idempotent
        floatx4 acc[4][4];
        #pragma unroll
        for (int i = 0; i < 4; ++i)
            #pragma unroll
            for (int j = 0; j < 4; ++j) acc[i][j] = (floatx4)0.0f;

        unsigned int bcur[4][4], bnxt[4][4];
        #pragma unroll
        for (int d = 0; d < 4; ++d)
            #pragma unroll
            for (int t = 0; t < 4; ++t) bcur[t][d] = bload(0, d, t);
        stage_dma(0, 0);
        __syncthreads();                             // drains DMA(0)

        #pragma unroll
        for (int st = 0; st < 4; ++st) {             // stages of 128 k
            const int p = st & 1;

            half2v s2[4];
            #pragma unroll
            for (int t = 0; t < 4; ++t) {
                const float f = s_base[(size_t)st * N_DIM + 16 * t];
                s2[t] = (half2v){ (_Float16)f, (_Float16)f };
            }

            if (st < 3) {
                #pragma unroll
                for (int d = 0; d < 4; ++d)
                    #pragma unroll
                    for (int t = 0; t < 4; ++t) bnxt[t][d] = bload(st + 1, d, t);
                stage_dma(st + 1, p ^ 1);
            }

            #pragma unroll
            for (int d = 0; d < 4; ++d) {            // k32 steps in stage
                half8 afr[4];
                #pragma unroll
                for (int mt = 0; mt < 4; ++mt)
                    afr[mt] = *(const half8*)(&astage[p][(d * 4 + mt) * 1024 + lane * 16]);
                #pragma unroll
                for (int t = 0; t < 4; ++t) {
                    const unsigned int wd = bcur[t][d];
                    const half2v sc = s2[t];
                    union { half2v h2[4]; half8 h8; } b8;
                    b8.h2[0] = dq_pair(( wd        & 0x000F000Fu) | 0x64006400u, c1032, sc);
                    b8.h2[1] = dq_pair(((wd >> 4)  & 0x000F000Fu) | 0x64006400u, c1032, sc);
                    b8.h2[2] = dq_pair(((wd >> 8)  & 0x000F000Fu) | 0x64006400u, c1032, sc);
                    b8.h2[3] = dq_pair(((wd >> 12) & 0x000F000Fu) | 0x64006400u, c1032, sc);
                    #pragma unroll
                    for (int mt = 0; mt < 4; ++mt)
                        acc[mt][t] = __builtin_amdgcn_mfma_f32_16x16x32_f16(
                            afr[mt], b8.h8, acc[mt][t], 0, 0, 0);
                }
            }
            __syncthreads();                         // DMA(st+1) complete
            if (st < 3) {
                #pragma unroll
                for (int d = 0; d < 4; ++d)
                    #pragma unroll
                    for (int t = 0; t < 4; ++t) bcur[t][d] = bnxt[t][d];
            }
        }

        // Store EVERY rep (identical values) so no rep is dead code.
        _Float16* pt = partial + (size_t)(kb * M_DIM) * N_DIM;
        #pragma unroll
        for (int mt = 0; mt < 4; ++mt)
            #pragma unroll
            for (int t = 0; t < 4; ++t)
                #pragma unroll
                for (int r = 0; r < 4; ++r) {
                    const int m = mt * 16 + q * 4 + r;
                    pt[(size_t)m * N_DIM + wc + 16 * t + c] = (_Float16)acc[mt][t][r];
                }
        __syncthreads();                             // astage safe for next rep
    }
}

__global__ __launch_bounds__(256) void reduce_kernel(
        const _Float16* __restrict__ partial, float* __restrict__ out) {
    const size_t i = ((size_t)blockIdx.x * 256 + threadIdx.x) * 8;
    const size_t S = (size_t)M_DIM * N_DIM;
    float a[8] = {0, 0, 0, 0, 0, 0, 0, 0};
    #pragma unroll
    for (int bk = 0; bk < KSB; ++bk) {
        const half8 hv = *(const half8*)(partial + bk * S + i);
        #pragma unroll
        for (int j = 0; j < 8; ++j) a[j] += (float)hv[j];
    }
    float4 v0 = { a[0], a[1], a[2], a[3] };
    float4 v1 = { a[4], a[5], a[6], a[7] };
    *(float4*)(out + i)     = v0;
    *(float4*)(out + i + 4) = v1;
}

extern "C" void kernel_launch(void* const* d_in, const int* in_sizes, int n_in,
                              void* d_out, int out_size, void* d_ws, size_t ws_size,
                              hipStream_t stream) {
    const float*        x  = (const float*)d_in[0];
    const unsigned int* Bq = (const unsigned int*)d_in[1];
    const float*        sc = (const float*)d_in[2];
    float* out        = (float*)d_out;
    _Float16* xp      = (_Float16*)d_ws;                      // 1 MB
    _Float16* partial = (_Float16*)((char*)d_ws + (1 << 20)); // KSB*1MB = 16 MB

    permute_x_kernel<<<dim3(M_DIM * K_DIM / 8 / 256), 256, 0, stream>>>(x, xp);
    machete_mm_kernel<<<dim3(N_DIM / NT, KSB), 512, 0, stream>>>(xp, Bq, sc, partial);
    reduce_kernel<<<dim3(M_DIM * N_DIM / (256 * 8)), 256, 0, stream>>>(partial, out);
}

// Round 10
// 96.206 us; speedup vs baseline: 3.2799x; 3.2799x over previous
//
#include <hip/hip_runtime.h>

typedef _Float16 half2v __attribute__((ext_vector_type(2)));
typedef _Float16 half8  __attribute__((ext_vector_type(8)));
typedef float    floatx4 __attribute__((ext_vector_type(4)));

#define M_DIM 64
#define K_DIM 8192
#define N_DIM 8192
#define NT 512              // cols per block (16 waves x 32 cols)
#define KSB 16              // k-chunks; chunk = 512 k = 4 stages x 128 k
#define BSTRIDE 516         // B LDS row stride in words (16B-aligned, bank-rot 4)
#define EPSTRIDE 520        // epilogue LDS row stride in fp16 (16B-aligned)

// x fp32 [64][8192] -> xp fp16 tiled [k/32][mt:4][lane:64][j:8]
// j-order within each 8 is sigma=(0,4,1,5,2,6,3,7) matching B nibble unpack.
__global__ __launch_bounds__(256) void permute_x_kernel(
        const float* __restrict__ x, _Float16* __restrict__ xp) {
    const int t  = blockIdx.x * 256 + threadIdx.x;
    const int c  = t & 15;
    const int q  = (t >> 4) & 3;
    const int mt = (t >> 6) & 3;
    const int kb = t >> 8;
    const int m  = mt * 16 + c;
    const int k0 = kb * 32 + q * 8;
    const float* src = x + (size_t)m * K_DIM + k0;
    float4 a = *(const float4*)(src);
    float4 b = *(const float4*)(src + 4);
    union { _Float16 h[8]; float4 f; } u;
    u.h[0] = (_Float16)a.x; u.h[1] = (_Float16)b.x;
    u.h[2] = (_Float16)a.y; u.h[3] = (_Float16)b.y;
    u.h[4] = (_Float16)a.z; u.h[5] = (_Float16)b.z;
    u.h[6] = (_Float16)a.w; u.h[7] = (_Float16)b.w;
    *(float4*)(xp + (size_t)t * 8) = u.f;
}

__device__ __forceinline__ void dma16(const void* g, void* l) {
    __builtin_amdgcn_global_load_lds(
        (const __attribute__((address_space(1))) unsigned int*)(uintptr_t)g,
        (__attribute__((address_space(3))) unsigned int*)(uintptr_t)l,
        16, 0, 0);
}

__device__ __forceinline__ half2v dq_pair(unsigned int bits, half2v sub, half2v sc) {
    union { unsigned int u; half2v h; } cv;
    cv.u = bits;
    return (cv.h - sub) * sc;      // v_pk_add_f16 + v_pk_mul_f16
}

__global__ __launch_bounds__(1024, 4) void machete_mm_kernel(
        const _Float16* __restrict__ xp,
        const unsigned int* __restrict__ Bq,
        const float* __restrict__ s,
        _Float16* __restrict__ partial) {
    // A dbuf 32KB | B dbuf 2x33KB (epilogue transpose buffer aliases B)
    __shared__ char lds[32768 + 2 * BSTRIDE * 16 * 4];
    char*         ablk  = lds;
    unsigned int* bblk  = (unsigned int*)(lds + 32768);
    _Float16*     ep    = (_Float16*)(lds + 32768);

    const int tid  = threadIdx.x;
    const int w    = tid >> 6;                       // wave 0..15, n-split
    const int lane = tid & 63;
    const int c    = lane & 15;
    const int q    = lane >> 4;
    const int ns   = blockIdx.x;                     // n-strip 0..15
    const int kb   = blockIdx.y;                     // k-chunk 0..15
    const int wc   = ns * NT + w * 32;               // wave's 32-col base

    const half2v c1032 = { (_Float16)1032.0f, (_Float16)1032.0f };

    // Scales: 4 groups (group == stage), 2 col-tiles per wave
    half2v s2[4][2];
    #pragma unroll
    for (int g = 0; g < 4; ++g) {
        const float f0 = s[(size_t)(kb * 4 + g) * N_DIM + wc + c];
        const float f1 = s[(size_t)(kb * 4 + g) * N_DIM + wc + 16 + c];
        s2[g][0] = (half2v){ (_Float16)f0, (_Float16)f0 };
        s2[g][1] = (half2v){ (_Float16)f1, (_Float16)f1 };
    }

    const char* a_base = (const char*)xp + (size_t)kb * 65536;
    const char* b_base = (const char*)Bq;

    // Stage DMA — ALL 1KB-contiguous wave transfers:
    //  A: 16KB, wave w copies chunk w.  B: 16 rows x 2KB, wave w copies row w.
    auto stage_dma = [&](int st, int p) {
        dma16(a_base + (size_t)st * 16384 + w * 1024 + lane * 16,
              ablk + p * 16384 + w * 1024);
        const size_t brow = (size_t)(kb * 64 + st * 16 + w) * N_DIM + ns * NT;
        unsigned int* bdst = bblk + p * (BSTRIDE * 16) + w * BSTRIDE;
        dma16(b_base + brow * 4 +        lane * 16, bdst);
        dma16(b_base + brow * 4 + 1024 + lane * 16, bdst + 256);
    };

    floatx4 acc[4][2];
    #pragma unroll
    for (int i = 0; i < 4; ++i) { acc[i][0] = (floatx4)0.0f; acc[i][1] = (floatx4)0.0f; }

    stage_dma(0, 0);
    __syncthreads();                                 // drains DMA(0)

    #pragma unroll
    for (int st = 0; st < 4; ++st) {                 // stages of 128 k
        const int p = st & 1;
        if (st < 3) stage_dma(st + 1, p ^ 1);

        const unsigned int* bs = bblk + p * (BSTRIDE * 16);
        #pragma unroll
        for (int d = 0; d < 4; ++d) {                // k32 steps in stage
            half8 afr[4];
            #pragma unroll
            for (int mt = 0; mt < 4; ++mt)
                afr[mt] = *(const half8*)(ablk + p * 16384 + (d * 4 + mt) * 1024 + lane * 16);
            #pragma unroll
            for (int t = 0; t < 2; ++t) {
                const unsigned int wd = bs[(d * 4 + q) * BSTRIDE + w * 32 + 16 * t + c];
                const half2v sc = s2[st][t];
                union { half2v h2[4]; half8 h8; } b8;
                b8.h2[0] = dq_pair(( wd        & 0x000F000Fu) | 0x64006400u, c1032, sc);
                b8.h2[1] = dq_pair(((wd >> 4)  & 0x000F000Fu) | 0x64006400u, c1032, sc);
                b8.h2[2] = dq_pair(((wd >> 8)  & 0x000F000Fu) | 0x64006400u, c1032, sc);
                b8.h2[3] = dq_pair(((wd >> 12) & 0x000F000Fu) | 0x64006400u, c1032, sc);
                #pragma unroll
                for (int mt = 0; mt < 4; ++mt)
                    acc[mt][t] = __builtin_amdgcn_mfma_f32_16x16x32_f16(
                        afr[mt], b8.h8, acc[mt][t], 0, 0, 0);
            }
        }
        __syncthreads();                             // DMA(st+1) complete
    }

    // Epilogue: LDS transpose (2 rounds x 32 rows) -> 1KB-contiguous stores.
    _Float16* pt = partial + (size_t)(kb * M_DIM) * N_DIM + ns * NT;
    #pragma unroll
    for (int r = 0; r < 2; ++r) {
        if (r) __syncthreads();
        #pragma unroll
        for (int h = 0; h < 2; ++h) {
            const int mt = 2 * r + h;
            const int ml = h * 16 + q * 4;           // local row base 0..31
            #pragma unroll
            for (int t = 0; t < 2; ++t)
                #pragma unroll
                for (int rr = 0; rr < 4; ++rr)
                    ep[(ml + rr) * EPSTRIDE + w * 32 + 16 * t + c] =
                        (_Float16)acc[mt][t][rr];
        }
        __syncthreads();
        // 1024 threads: 32 rows x 1KB; thread -> 32B of one row.
        const int row = tid >> 5;                    // 0..31
        const int seg = tid & 31;                    // 16-halfword segment
        const _Float16* src = ep + row * EPSTRIDE + seg * 16;
        uint4 u0 = *(const uint4*)(src);
        uint4 u1 = *(const uint4*)(src + 8);
        _Float16* dst = pt + (size_t)(r * 32 + row) * N_DIM + seg * 16;
        *(uint4*)(dst)     = u0;
        *(uint4*)(dst + 8) = u1;
    }
}

__global__ __launch_bounds__(256) void reduce_kernel(
        const _Float16* __restrict__ partial, float* __restrict__ out) {
    const size_t i = ((size_t)blockIdx.x * 256 + threadIdx.x) * 8;
    const size_t S = (size_t)M_DIM * N_DIM;
    float a[8] = {0, 0, 0, 0, 0, 0, 0, 0};
    #pragma unroll
    for (int bk = 0; bk < KSB; ++bk) {
        const half8 hv = *(const half8*)(partial + bk * S + i);
        #pragma unroll
        for (int j = 0; j < 8; ++j) a[j] += (float)hv[j];
    }
    float4 v0 = { a[0], a[1], a[2], a[3] };
    float4 v1 = { a[4], a[5], a[6], a[7] };
    *(float4*)(out + i)     = v0;
    *(float4*)(out + i + 4) = v1;
}

extern "C" void kernel_launch(void* const* d_in, const int* in_sizes, int n_in,
                              void* d_out, int out_size, void* d_ws, size_t ws_size,
                              hipStream_t stream) {
    const float*        x  = (const float*)d_in[0];
    const unsigned int* Bq = (const unsigned int*)d_in[1];
    const float*        sc = (const float*)d_in[2];
    float* out        = (float*)d_out;
    _Float16* xp      = (_Float16*)d_ws;                      // 1 MB
    _Float16* partial = (_Float16*)((char*)d_ws + (1 << 20)); // KSB*1MB = 16 MB

    permute_x_kernel<<<dim3(M_DIM * K_DIM / 8 / 256), 256, 0, stream>>>(x, xp);
    machete_mm_kernel<<<dim3(N_DIM / NT, KSB), 1024, 0, stream>>>(xp, Bq, sc, partial);
    reduce_kernel<<<dim3(M_DIM * N_DIM / (256 * 8)), 256, 0, stream>>>(partial, out);
}